// Round 12
// baseline (130.264 us; speedup 1.0000x reference)
//
#include <hip/hip_runtime.h>
#include <hip/hip_bf16.h>

#define N_NODES 20000
#define N_EDGES 2000
#define IN_FEATS 128
#define NUM_HEADS 4
#define OUT_FEATS 32
#define EDGE_DIM 64
#define C_FEATS 128   // NUM_HEADS*OUT_FEATS
#define NEG_SLOPE 0.2f
#define MAXD 256      // max pairs/edge bucket (mean 110, max~160, +14 sigma safe)
#define WT_LD 136     // padded LDS row (bf16 elems)
#define NTILES (N_NODES / 16)        // 1250 proj m-tiles
#define PROJ_BLKS ((NTILES + 3) / 4) // 313 proj blocks (4 waves each)
#define K1_BLK 512
#define K1_THR 256
#define CUR_STRIDE 16 // cursor padded to 1 counter / 64B line (atomic-serialization fix)

typedef __attribute__((ext_vector_type(8))) short bf16x8;
typedef __attribute__((ext_vector_type(4))) float f32x4;

__device__ __forceinline__ float leaky(float x) { return (x > 0.f) ? x : NEG_SLOPE * x; }
__device__ __forceinline__ unsigned short f2bf(float x) {
    __hip_bfloat16 h = __float2bfloat16(x);
    return *reinterpret_cast<unsigned short*>(&h);
}

// ---------------------------------------------------------------------------
// K1: blocks 0..PROJ_BLKS-1: MFMA projection; blocks PROJ_BLKS..511: bucket
// scatter + node_start... plus ALL blocks grid-stride zero `out` (10MB) so K2
// can scatter-add into it (dispatch boundary orders zero -> atomics).
// Plain stores everywhere (R11 lesson: NT stores cost ~5us net).
// ---------------------------------------------------------------------------
__global__ __launch_bounds__(K1_THR) void proj_scatter_kernel(
    const float* __restrict__ feat, const float* __restrict__ fc_w,
    const float* __restrict__ attn_src,
    const int* __restrict__ src_idx, const int* __restrict__ edge_idx, int P,
    __hip_bfloat16* __restrict__ feat_bf, float* __restrict__ s_buf,
    int* __restrict__ cursor, int* __restrict__ node_start, int* __restrict__ edge_nodes,
    float* __restrict__ out)
{
    __shared__ unsigned short Wt[128 * WT_LD];
    const int t = threadIdx.x;
    const int bid = blockIdx.x;

    // zero the output accumulator (grid-stride, float4)
    {
        const f32x4 z = {0.f, 0.f, 0.f, 0.f};
        const size_t total4 = (size_t)N_NODES * C_FEATS / 4;
        for (size_t i = (size_t)bid * K1_THR + t; i < total4; i += (size_t)K1_BLK * K1_THR)
            *(f32x4*)&out[i * 4] = z;
    }

    if (bid < PROJ_BLKS) {
        for (int q = t; q < 64 * 128; q += K1_THR) {
            const int c = q & 127, k = (q >> 7) * 2;
            Wt[c * WT_LD + k]     = f2bf(fc_w[k * C_FEATS + c]);
            Wt[c * WT_LD + k + 1] = f2bf(fc_w[(k + 1) * C_FEATS + c]);
        }
        __syncthreads();

        const int wave = t >> 6, lane = t & 63;
        const int wid = bid * 4 + wave;
        if (wid < NTILES) {
            const int m0 = wid * 16;
            const int lrow = lane & 15, lk = lane >> 4;

            bf16x8 afr[4];
            const float* arow = feat + (size_t)(m0 + lrow) * IN_FEATS + lk * 8;
            #pragma unroll
            for (int kt = 0; kt < 4; ++kt) {
                const float4 f0 = *(const float4*)(arow + kt * 32);
                const float4 f1 = *(const float4*)(arow + kt * 32 + 4);
                bf16x8 a;
                a[0] = (short)f2bf(f0.x); a[1] = (short)f2bf(f0.y);
                a[2] = (short)f2bf(f0.z); a[3] = (short)f2bf(f0.w);
                a[4] = (short)f2bf(f1.x); a[5] = (short)f2bf(f1.y);
                a[6] = (short)f2bf(f1.z); a[7] = (short)f2bf(f1.w);
                afr[kt] = a;
            }

            f32x4 acc[8];
            #pragma unroll
            for (int nt = 0; nt < 8; ++nt) acc[nt] = (f32x4){0.f, 0.f, 0.f, 0.f};
            #pragma unroll
            for (int nt = 0; nt < 8; ++nt) {
                const unsigned short* wrow = &Wt[(nt * 16 + lrow) * WT_LD + lk * 8];
                #pragma unroll
                for (int kt = 0; kt < 4; ++kt) {
                    const bf16x8 b = *(const bf16x8*)(wrow + kt * 32);
                    acc[nt] = __builtin_amdgcn_mfma_f32_16x16x32_bf16(afr[kt], b, acc[nt], 0, 0, 0);
                }
            }

            // C layout: col = lane&15, row = (lane>>4)*4 + reg  (m89-verified)
            #pragma unroll
            for (int nt = 0; nt < 8; ++nt) {
                const int c = nt * 16 + lrow;
                #pragma unroll
                for (int r = 0; r < 4; ++r)
                    feat_bf[(size_t)(m0 + lk * 4 + r) * C_FEATS + c] = __float2bfloat16(acc[nt][r]);
            }
            float aw[8];
            #pragma unroll
            for (int nt = 0; nt < 8; ++nt) aw[nt] = attn_src[nt * 16 + lrow];
            #pragma unroll
            for (int h = 0; h < NUM_HEADS; ++h) {
                #pragma unroll
                for (int r = 0; r < 4; ++r) {
                    float v = acc[2 * h][r] * aw[2 * h] + acc[2 * h + 1][r] * aw[2 * h + 1];
                    v += __shfl_xor(v, 1);
                    v += __shfl_xor(v, 2);
                    v += __shfl_xor(v, 4);
                    v += __shfl_xor(v, 8);
                    if (lrow == 0) s_buf[(m0 + lk * 4 + r) * NUM_HEADS + h] = v;
                }
            }
        }
    } else {
        const int nthreads = (K1_BLK - PROJ_BLKS) * K1_THR;
        for (int p = (bid - PROJ_BLKS) * K1_THR + t; p < P; p += nthreads) {
            const int e = edge_idx[p];
            const int s = src_idx[p];
            const int pos = atomicAdd(&cursor[e * CUR_STRIDE], 1);
            if (pos < MAXD) edge_nodes[e * MAXD + pos] = s;
            const int prev = (p == 0) ? -1 : src_idx[p - 1];
            for (int n = prev + 1; n <= s; ++n) node_start[n] = p;
            if (p == P - 1)
                for (int n = s + 1; n <= N_NODES; ++n) node_start[n] = P;
        }
    }
}

// ---------------------------------------------------------------------------
// K2: per-edge softmax + aggregation + DIRECT scatter-add into out (replaces
// the disseminate kernel + its dispatch boundary). Block = 1 edge, 512 thr =
// 8 wave-substreams. After the hef row is reduced, all 512 threads scatter it:
// thread (grp=t>>7, c=t&127) adds row[c] to out[n_j*128+c] for j = grp,grp+4,..
// ~14k f32 atomics per block, ~11 per out address -> low contention.
// ---------------------------------------------------------------------------
__global__ __launch_bounds__(512) void edge_attn_kernel(
    const float* __restrict__ s_buf, const float* __restrict__ edge_feat,
    const float* __restrict__ attn_edge, const __hip_bfloat16* __restrict__ feat_bf,
    const int* __restrict__ cursor, const int* __restrict__ edge_nodes,
    float* __restrict__ out)
{
    __shared__ float4 w_sh[MAXD];
    __shared__ int    n_sh[MAXD];
    __shared__ float  te_sh[NUM_HEADS];
    __shared__ float  inv_sh[NUM_HEADS];
    __shared__ float  wred[8][NUM_HEADS];
    __shared__ float  red[8][C_FEATS];
    __shared__ float  row_sh[C_FEATS];

    const int e = blockIdx.x;
    const int t = threadIdx.x;
    const int wv = t >> 6, lane = t & 63;

    // fused edge projection te[h] = <edge_feat[e,:], attn_edge[h,:]> (wave 0)
    if (t < EDGE_DIM) {
        const float v = edge_feat[e * EDGE_DIM + t];
        #pragma unroll
        for (int h = 0; h < NUM_HEADS; ++h) {
            float p = v * attn_edge[h * EDGE_DIM + t];
            p += __shfl_xor(p, 32); p += __shfl_xor(p, 16); p += __shfl_xor(p, 8);
            p += __shfl_xor(p, 4);  p += __shfl_xor(p, 2);  p += __shfl_xor(p, 1);
            if (t == 0) te_sh[h] = p;
        }
    }
    __syncthreads();

    const int m = min(cursor[e * CUR_STRIDE], MAXD);
    const int m_pad = (m + 31) & ~31;

    float ps0 = 0.f, ps1 = 0.f, ps2 = 0.f, ps3 = 0.f;
    if (t < m) {
        const int n = edge_nodes[e * MAXD + t];
        n_sh[t] = n;
        const float4 s4 = *(const float4*)&s_buf[n * NUM_HEADS];
        float4 w;
        w.x = __expf(leaky(s4.x + te_sh[0]));
        w.y = __expf(leaky(s4.y + te_sh[1]));
        w.z = __expf(leaky(s4.z + te_sh[2]));
        w.w = __expf(leaky(s4.w + te_sh[3]));
        w_sh[t] = w;
        ps0 = w.x; ps1 = w.y; ps2 = w.z; ps3 = w.w;
    } else if (t < m_pad) {
        n_sh[t] = 0;
        w_sh[t] = make_float4(0.f, 0.f, 0.f, 0.f);   // exact no-op in all sums
    }
    #pragma unroll
    for (int d = 32; d >= 1; d >>= 1) {
        ps0 += __shfl_xor(ps0, d); ps1 += __shfl_xor(ps1, d);
        ps2 += __shfl_xor(ps2, d); ps3 += __shfl_xor(ps3, d);
    }
    if (lane == 0) {
        wred[wv][0] = ps0; wred[wv][1] = ps1; wred[wv][2] = ps2; wred[wv][3] = ps3;
    }
    __syncthreads();
    if (t < NUM_HEADS) {
        float s = 0.f;
        #pragma unroll
        for (int w8 = 0; w8 < 8; ++w8) s += wred[w8][t];
        inv_sh[t] = 1.f / (s + 1e-9f);
    }
    __syncthreads();

    // aggregation: substream wv (0..7) handles j = wv, wv+8, ...; branch-free
    const int c0 = lane * 2;
    const int h = lane >> 4;
    float a0 = 0.f, a1 = 0.f;
    const unsigned short* fb = (const unsigned short*)feat_bf;
    #pragma unroll 8
    for (int j = wv; j < m_pad; j += 8) {
        const int n = n_sh[j];
        const float w = ((const float*)&w_sh[j])[h];
        const unsigned v = *(const unsigned*)(fb + (size_t)n * C_FEATS + c0);
        a0 += w * __uint_as_float(v << 16);
        a1 += w * __uint_as_float(v & 0xffff0000u);
    }
    red[wv][c0] = a0;
    red[wv][c0 + 1] = a1;
    __syncthreads();
    if (t < C_FEATS) {
        float r = 0.f;
        #pragma unroll
        for (int w8 = 0; w8 < 8; ++w8) r += red[w8][t];
        row_sh[t] = r * inv_sh[t >> 5];
    }
    __syncthreads();

    // scatter-add the finished row into out for every node of this edge.
    // NOTE: bound is the REAL m (padding entries would corrupt node 0).
    const int c = t & 127;
    const int grp = t >> 7;          // 0..3
    const float rc = row_sh[c];
    for (int j = grp; j < m; j += 4) {
        atomicAdd(&out[(size_t)n_sh[j] * C_FEATS + c], rc);
    }
}

extern "C" void kernel_launch(void* const* d_in, const int* in_sizes, int n_in,
                              void* d_out, int out_size, void* d_ws, size_t ws_size,
                              hipStream_t stream) {
    const float* feat      = (const float*)d_in[0];
    const float* edge_feat = (const float*)d_in[1];
    // d_in[2] = H (dense incidence) — intentionally unused
    const float* fc_w      = (const float*)d_in[3];
    const float* attn_src  = (const float*)d_in[4];
    const float* attn_edge = (const float*)d_in[5];
    const int*   src_idx   = (const int*)d_in[6];
    const int*   edge_idx  = (const int*)d_in[7];
    const int P = in_sizes[6];
    float* out = (float*)d_out;

    float* ws = (float*)d_ws;
    float*          s_buf      = ws;                                          // 20000*4 f32
    __hip_bfloat16* feat_bf    = (__hip_bfloat16*)(s_buf + N_NODES * NUM_HEADS); // 20000*128 bf16
    int*            node_start = (int*)(feat_bf + (size_t)N_NODES * C_FEATS); // 20001
    int*            edge_nodes = node_start + (N_NODES + 1);                  // 2000*MAXD
    int*            cursor     = edge_nodes + N_EDGES * MAXD;                 // 2000*CUR_STRIDE

    hipMemsetAsync(cursor, 0, N_EDGES * CUR_STRIDE * sizeof(int), stream);
    proj_scatter_kernel<<<K1_BLK, K1_THR, 0, stream>>>(
        feat, fc_w, attn_src, src_idx, edge_idx, P,
        feat_bf, s_buf, cursor, node_start, edge_nodes, out);
    edge_attn_kernel<<<N_EDGES, 512, 0, stream>>>(
        s_buf, edge_feat, attn_edge, feat_bf, cursor, edge_nodes, out);
}

// Round 13
// 50.403 us; speedup vs baseline: 2.5845x; 2.5845x over previous
//
#include <hip/hip_runtime.h>
#include <hip/hip_bf16.h>

#define N_NODES 20000
#define N_EDGES 2000
#define IN_FEATS 128
#define NUM_HEADS 4
#define OUT_FEATS 32
#define EDGE_DIM 64
#define C_FEATS 128   // NUM_HEADS*OUT_FEATS
#define NEG_SLOPE 0.2f
#define MAXD 256      // max pairs/edge bucket (mean 110, max~160, +14 sigma safe)
#define WT_LD 136     // padded LDS row (bf16 elems)
#define NTILES (N_NODES / 16)        // 1250 proj m-tiles
#define PROJ_BLKS ((NTILES + 3) / 4) // 313 proj blocks (4 waves each)
#define K1_BLK 512
#define K1_THR 256
#define CUR_STRIDE 16 // cursor padded to 1 counter / 64B line (atomic-serialization fix)

typedef __attribute__((ext_vector_type(8))) short bf16x8;
typedef __attribute__((ext_vector_type(4))) float f32x4;

__device__ __forceinline__ float leaky(float x) { return (x > 0.f) ? x : NEG_SLOPE * x; }
__device__ __forceinline__ unsigned short f2bf(float x) {
    __hip_bfloat16 h = __float2bfloat16(x);
    return *reinterpret_cast<unsigned short*>(&h);
}

// ---------------------------------------------------------------------------
// K0: zero the cursor array ourselves. R12 decomposition + rocprof rows
// (125.97KB fill @ ~93us) implicate the runtime's fillBufferAligned path for
// small fills; a hand-rolled 128KB zero kernel is ~2us of actual work.
// ---------------------------------------------------------------------------
__global__ __launch_bounds__(256) void zero_cursor_kernel(f32x4* __restrict__ p) {
    const int i = blockIdx.x * 256 + threadIdx.x;  // 64 blocks * 256 thr * 2 iters
    const f32x4 z = {0.f, 0.f, 0.f, 0.f};
    p[i] = z;
    p[i + 16384] = z;
}

// ---------------------------------------------------------------------------
// K1: blocks 0..PROJ_BLKS-1: MFMA projection; blocks PROJ_BLKS..511: bucket
// scatter + node_start build. (R7/R9 structure, plain stores — R11: NT hurts.)
// ---------------------------------------------------------------------------
__global__ __launch_bounds__(K1_THR) void proj_scatter_kernel(
    const float* __restrict__ feat, const float* __restrict__ fc_w,
    const float* __restrict__ attn_src,
    const int* __restrict__ src_idx, const int* __restrict__ edge_idx, int P,
    __hip_bfloat16* __restrict__ feat_bf, float* __restrict__ s_buf,
    int* __restrict__ cursor, int* __restrict__ node_start, int* __restrict__ edge_nodes)
{
    __shared__ unsigned short Wt[128 * WT_LD];
    const int t = threadIdx.x;
    const int bid = blockIdx.x;

    if (bid < PROJ_BLKS) {
        for (int q = t; q < 64 * 128; q += K1_THR) {
            const int c = q & 127, k = (q >> 7) * 2;
            Wt[c * WT_LD + k]     = f2bf(fc_w[k * C_FEATS + c]);
            Wt[c * WT_LD + k + 1] = f2bf(fc_w[(k + 1) * C_FEATS + c]);
        }
        __syncthreads();

        const int wave = t >> 6, lane = t & 63;
        const int wid = bid * 4 + wave;
        if (wid < NTILES) {
            const int m0 = wid * 16;
            const int lrow = lane & 15, lk = lane >> 4;

            bf16x8 afr[4];
            const float* arow = feat + (size_t)(m0 + lrow) * IN_FEATS + lk * 8;
            #pragma unroll
            for (int kt = 0; kt < 4; ++kt) {
                const float4 f0 = *(const float4*)(arow + kt * 32);
                const float4 f1 = *(const float4*)(arow + kt * 32 + 4);
                bf16x8 a;
                a[0] = (short)f2bf(f0.x); a[1] = (short)f2bf(f0.y);
                a[2] = (short)f2bf(f0.z); a[3] = (short)f2bf(f0.w);
                a[4] = (short)f2bf(f1.x); a[5] = (short)f2bf(f1.y);
                a[6] = (short)f2bf(f1.z); a[7] = (short)f2bf(f1.w);
                afr[kt] = a;
            }

            f32x4 acc[8];
            #pragma unroll
            for (int nt = 0; nt < 8; ++nt) acc[nt] = (f32x4){0.f, 0.f, 0.f, 0.f};
            #pragma unroll
            for (int nt = 0; nt < 8; ++nt) {
                const unsigned short* wrow = &Wt[(nt * 16 + lrow) * WT_LD + lk * 8];
                #pragma unroll
                for (int kt = 0; kt < 4; ++kt) {
                    const bf16x8 b = *(const bf16x8*)(wrow + kt * 32);
                    acc[nt] = __builtin_amdgcn_mfma_f32_16x16x32_bf16(afr[kt], b, acc[nt], 0, 0, 0);
                }
            }

            // C layout: col = lane&15, row = (lane>>4)*4 + reg  (m89-verified)
            #pragma unroll
            for (int nt = 0; nt < 8; ++nt) {
                const int c = nt * 16 + lrow;
                #pragma unroll
                for (int r = 0; r < 4; ++r)
                    feat_bf[(size_t)(m0 + lk * 4 + r) * C_FEATS + c] = __float2bfloat16(acc[nt][r]);
            }
            float aw[8];
            #pragma unroll
            for (int nt = 0; nt < 8; ++nt) aw[nt] = attn_src[nt * 16 + lrow];
            #pragma unroll
            for (int h = 0; h < NUM_HEADS; ++h) {
                #pragma unroll
                for (int r = 0; r < 4; ++r) {
                    float v = acc[2 * h][r] * aw[2 * h] + acc[2 * h + 1][r] * aw[2 * h + 1];
                    v += __shfl_xor(v, 1);
                    v += __shfl_xor(v, 2);
                    v += __shfl_xor(v, 4);
                    v += __shfl_xor(v, 8);
                    if (lrow == 0) s_buf[(m0 + lk * 4 + r) * NUM_HEADS + h] = v;
                }
            }
        }
    } else {
        const int nthreads = (K1_BLK - PROJ_BLKS) * K1_THR;
        for (int p = (bid - PROJ_BLKS) * K1_THR + t; p < P; p += nthreads) {
            const int e = edge_idx[p];
            const int s = src_idx[p];
            const int pos = atomicAdd(&cursor[e * CUR_STRIDE], 1);
            if (pos < MAXD) edge_nodes[e * MAXD + pos] = s;
            const int prev = (p == 0) ? -1 : src_idx[p - 1];
            for (int n = prev + 1; n <= s; ++n) node_start[n] = p;
            if (p == P - 1)
                for (int n = s + 1; n <= N_NODES; ++n) node_start[n] = P;
        }
    }
}

// ---------------------------------------------------------------------------
// K2: per-edge softmax + aggregation. Block = 1 edge (2000 blocks), 512 thr =
// 8 wave-substreams. Edge-proj head parallel across 4 waves (head = wv&3).
// Max-free softmax; staging padded to x32 with w=0 -> branch-free aggregation.
// hef written bf16 normal stores (K3 re-reads it ~11x; wants L2 residency).
// ---------------------------------------------------------------------------
__global__ __launch_bounds__(512) void edge_attn_kernel(
    const float* __restrict__ s_buf, const float* __restrict__ edge_feat,
    const float* __restrict__ attn_edge, const __hip_bfloat16* __restrict__ feat_bf,
    const int* __restrict__ cursor, const int* __restrict__ edge_nodes,
    __hip_bfloat16* __restrict__ hef)
{
    __shared__ float4 w_sh[MAXD];
    __shared__ int    n_sh[MAXD];
    __shared__ float  te_sh[NUM_HEADS];
    __shared__ float  inv_sh[NUM_HEADS];
    __shared__ float  wred[8][NUM_HEADS];
    __shared__ float  red[8][C_FEATS];

    const int e = blockIdx.x;
    const int t = threadIdx.x;
    const int wv = t >> 6, lane = t & 63;

    // fused edge projection: wave wv (0..3) computes head wv; waves 4..7 idle here
    if (wv < NUM_HEADS) {
        const float v = (lane < EDGE_DIM) ? edge_feat[e * EDGE_DIM + lane] *
                                            attn_edge[wv * EDGE_DIM + lane] : 0.f;
        float p = v;
        p += __shfl_xor(p, 32); p += __shfl_xor(p, 16); p += __shfl_xor(p, 8);
        p += __shfl_xor(p, 4);  p += __shfl_xor(p, 2);  p += __shfl_xor(p, 1);
        if (lane == 0) te_sh[wv] = p;
    }
    __syncthreads();

    const int m = min(cursor[e * CUR_STRIDE], MAXD);
    const int m_pad = (m + 31) & ~31;

    float ps0 = 0.f, ps1 = 0.f, ps2 = 0.f, ps3 = 0.f;
    if (t < m) {
        const int n = edge_nodes[e * MAXD + t];
        n_sh[t] = n;
        const float4 s4 = *(const float4*)&s_buf[n * NUM_HEADS];
        float4 w;
        w.x = __expf(leaky(s4.x + te_sh[0]));
        w.y = __expf(leaky(s4.y + te_sh[1]));
        w.z = __expf(leaky(s4.z + te_sh[2]));
        w.w = __expf(leaky(s4.w + te_sh[3]));
        w_sh[t] = w;
        ps0 = w.x; ps1 = w.y; ps2 = w.z; ps3 = w.w;
    } else if (t < m_pad) {
        n_sh[t] = 0;
        w_sh[t] = make_float4(0.f, 0.f, 0.f, 0.f);   // exact no-op in all sums
    }
    #pragma unroll
    for (int d = 32; d >= 1; d >>= 1) {
        ps0 += __shfl_xor(ps0, d); ps1 += __shfl_xor(ps1, d);
        ps2 += __shfl_xor(ps2, d); ps3 += __shfl_xor(ps3, d);
    }
    if (lane == 0) {
        wred[wv][0] = ps0; wred[wv][1] = ps1; wred[wv][2] = ps2; wred[wv][3] = ps3;
    }
    __syncthreads();
    if (t < NUM_HEADS) {
        float s = 0.f;
        #pragma unroll
        for (int w8 = 0; w8 < 8; ++w8) s += wred[w8][t];
        inv_sh[t] = 1.f / (s + 1e-9f);
    }
    __syncthreads();

    // aggregation: substream wv (0..7) handles j = wv, wv+8, ...; branch-free
    const int c0 = lane * 2;
    const int h = lane >> 4;
    float a0 = 0.f, a1 = 0.f;
    const unsigned short* fb = (const unsigned short*)feat_bf;
    #pragma unroll 8
    for (int j = wv; j < m_pad; j += 8) {
        const int n = n_sh[j];
        const float w = ((const float*)&w_sh[j])[h];
        const unsigned v = *(const unsigned*)(fb + (size_t)n * C_FEATS + c0);
        a0 += w * __uint_as_float(v << 16);
        a1 += w * __uint_as_float(v & 0xffff0000u);
    }
    red[wv][c0] = a0;
    red[wv][c0 + 1] = a1;
    __syncthreads();
    if (t < C_FEATS) {
        float r = 0.f;
        #pragma unroll
        for (int w8 = 0; w8 < 8; ++w8) r += red[w8][t];
        hef[e * C_FEATS + t] = __float2bfloat16(r * inv_sh[t >> 5]);
    }
}

// ---------------------------------------------------------------------------
// K3: disseminate. 2500 blocks x 8 nodes, 256 threads = 4 waves; each wave
// owns 2 nodes, each lane 2 bf16 channels -> one wave load = one full 256B
// hef row (L2-resident, 512KB). (R9 structure, plain stores.)
// ---------------------------------------------------------------------------
#define K3_NODES 8
#define K3_CHUNK 512
__global__ __launch_bounds__(256) void disseminate_kernel(
    const int* __restrict__ node_start, const int* __restrict__ edge_idx,
    const __hip_bfloat16* __restrict__ hef, float* __restrict__ out)
{
    __shared__ int e_sh[K3_CHUNK];
    __shared__ int ns_sh[K3_NODES + 1];
    const int t = threadIdx.x;
    const int wv = t >> 6, lane = t & 63;
    const int c0 = lane * 2;
    const int n0 = blockIdx.x * K3_NODES;

    if (t < K3_NODES + 1) ns_sh[t] = node_start[n0 + t];
    __syncthreads();
    const int s0 = ns_sh[0], s1 = ns_sh[K3_NODES];

    float a00 = 0.f, a01 = 0.f, a10 = 0.f, a11 = 0.f;  // [node r][chan 0/1]
    const unsigned short* hu = (const unsigned short*)hef;

    for (int cb = s0; cb < s1; cb += K3_CHUNK) {
        const int ccnt = min(K3_CHUNK, s1 - cb);
        __syncthreads();
        for (int i = t; i < ccnt; i += 256) e_sh[i] = edge_idx[cb + i];
        __syncthreads();
        {
            const int jlo = max(ns_sh[wv * 2], cb);
            const int jhi = min(ns_sh[wv * 2 + 1], cb + ccnt);
            #pragma unroll 8
            for (int j = jlo; j < jhi; ++j) {
                const unsigned v = *(const unsigned*)(hu + (size_t)e_sh[j - cb] * C_FEATS + c0);
                a00 += __uint_as_float(v << 16);
                a01 += __uint_as_float(v & 0xffff0000u);
            }
        }
        {
            const int jlo = max(ns_sh[wv * 2 + 1], cb);
            const int jhi = min(ns_sh[wv * 2 + 2], cb + ccnt);
            #pragma unroll 8
            for (int j = jlo; j < jhi; ++j) {
                const unsigned v = *(const unsigned*)(hu + (size_t)e_sh[j - cb] * C_FEATS + c0);
                a10 += __uint_as_float(v << 16);
                a11 += __uint_as_float(v & 0xffff0000u);
            }
        }
    }
    *(float2*)&out[(size_t)(n0 + wv * 2)     * C_FEATS + c0] = make_float2(a00, a01);
    *(float2*)&out[(size_t)(n0 + wv * 2 + 1) * C_FEATS + c0] = make_float2(a10, a11);
}

extern "C" void kernel_launch(void* const* d_in, const int* in_sizes, int n_in,
                              void* d_out, int out_size, void* d_ws, size_t ws_size,
                              hipStream_t stream) {
    const float* feat      = (const float*)d_in[0];
    const float* edge_feat = (const float*)d_in[1];
    // d_in[2] = H (dense incidence) — intentionally unused
    const float* fc_w      = (const float*)d_in[3];
    const float* attn_src  = (const float*)d_in[4];
    const float* attn_edge = (const float*)d_in[5];
    const int*   src_idx   = (const int*)d_in[6];
    const int*   edge_idx  = (const int*)d_in[7];
    const int P = in_sizes[6];
    float* out = (float*)d_out;

    float* ws = (float*)d_ws;
    float*          s_buf      = ws;                                          // 20000*4 f32
    __hip_bfloat16* hef        = (__hip_bfloat16*)(s_buf + N_NODES * NUM_HEADS); // 2000*128 bf16
    __hip_bfloat16* feat_bf    = hef + N_EDGES * C_FEATS;                     // 20000*128 bf16
    int*            node_start = (int*)(feat_bf + (size_t)N_NODES * C_FEATS); // 20001
    int*            edge_nodes = node_start + (N_NODES + 1);                  // 2000*MAXD
    int*            cursor     = edge_nodes + N_EDGES * MAXD;                 // 2000*CUR_STRIDE (16B-aligned)

    zero_cursor_kernel<<<64, 256, 0, stream>>>((f32x4*)cursor);
    proj_scatter_kernel<<<K1_BLK, K1_THR, 0, stream>>>(
        feat, fc_w, attn_src, src_idx, edge_idx, P,
        feat_bf, s_buf, cursor, node_start, edge_nodes);
    edge_attn_kernel<<<N_EDGES, 512, 0, stream>>>(
        s_buf, edge_feat, attn_edge, feat_bf, cursor, edge_nodes, hef);
    disseminate_kernel<<<N_NODES / K3_NODES, 256, 0, stream>>>(
        node_start, edge_idx, hef, out);
}

// Round 14
// 48.289 us; speedup vs baseline: 2.6976x; 1.0438x over previous
//
#include <hip/hip_runtime.h>
#include <hip/hip_bf16.h>

#define N_NODES 20000
#define N_EDGES 2000
#define IN_FEATS 128
#define NUM_HEADS 4
#define OUT_FEATS 32
#define EDGE_DIM 64
#define C_FEATS 128   // NUM_HEADS*OUT_FEATS
#define NEG_SLOPE 0.2f
#define MAXD 256      // max pairs/edge bucket (mean 110, max~160, +14 sigma safe)
#define WT_LD 136     // padded LDS row (bf16 elems)
#define NTILES (N_NODES / 16)        // 1250 proj m-tiles
#define PROJ_BLKS ((NTILES + 3) / 4) // 313 proj blocks (4 waves each)
#define K1_BLK 512
#define K1_THR 256
#define CUR_STRIDE 16 // cursor padded to 1 counter / 64B line (atomic-serialization fix)

typedef __attribute__((ext_vector_type(8))) short bf16x8;
typedef __attribute__((ext_vector_type(4))) float f32x4;

__device__ __forceinline__ float leaky(float x) { return (x > 0.f) ? x : NEG_SLOPE * x; }
__device__ __forceinline__ unsigned short f2bf(float x) {
    __hip_bfloat16 h = __float2bfloat16(x);
    return *reinterpret_cast<unsigned short*>(&h);
}

// ---------------------------------------------------------------------------
// K0: zero cursor (exact 128KB this time) + pre-convert fc_w into a transposed
// bf16 global buffer wt_g[c][k] (32KB). Removes the per-proj-block re-read/
// re-convert of fc_w (313 x 64KB L2 + 5M converts) from K1's critical path.
// ---------------------------------------------------------------------------
__global__ __launch_bounds__(256) void prep_kernel(
    f32x4* __restrict__ cursor4, const float* __restrict__ fc_w,
    unsigned short* __restrict__ wt_g)
{
    const int i = blockIdx.x * 256 + threadIdx.x;   // 64 blocks x 256 = 16384
    if (i < (N_EDGES * CUR_STRIDE) / 4)             // 8192 f32x4 = 128KB
        cursor4[i] = (f32x4){0.f, 0.f, 0.f, 0.f};
    // one element each: wt_g[c*128 + k] = bf16(fc_w[k*128 + c])
    const int c = i & 127, k = i >> 7;
    wt_g[c * IN_FEATS + k] = f2bf(fc_w[k * C_FEATS + c]);
}

// ---------------------------------------------------------------------------
// K1: blocks 0..PROJ_BLKS-1: MFMA projection (stages pre-converted wt_g by
// straight uint copy); blocks PROJ_BLKS..511: bucket scatter + node_start.
// ---------------------------------------------------------------------------
__global__ __launch_bounds__(K1_THR) void proj_scatter_kernel(
    const float* __restrict__ feat, const unsigned short* __restrict__ wt_g,
    const float* __restrict__ attn_src,
    const int* __restrict__ src_idx, const int* __restrict__ edge_idx, int P,
    __hip_bfloat16* __restrict__ feat_bf, float* __restrict__ s_buf,
    int* __restrict__ cursor, int* __restrict__ node_start, int* __restrict__ edge_nodes)
{
    __shared__ unsigned short Wt[128 * WT_LD];
    const int t = threadIdx.x;
    const int bid = blockIdx.x;

    if (bid < PROJ_BLKS) {
        // stage wt_g rows into padded LDS rows as uints (2 bf16 each): 8192 uints
        {
            const unsigned* src = (const unsigned*)wt_g;
            for (int q = t; q < 128 * 64; q += K1_THR) {
                const int c = q >> 6, kp = q & 63;
                ((unsigned*)&Wt[c * WT_LD])[kp] = src[c * 64 + kp];
            }
        }
        __syncthreads();

        const int wave = t >> 6, lane = t & 63;
        const int wid = bid * 4 + wave;
        if (wid < NTILES) {
            const int m0 = wid * 16;
            const int lrow = lane & 15, lk = lane >> 4;

            bf16x8 afr[4];
            const float* arow = feat + (size_t)(m0 + lrow) * IN_FEATS + lk * 8;
            #pragma unroll
            for (int kt = 0; kt < 4; ++kt) {
                const float4 f0 = *(const float4*)(arow + kt * 32);
                const float4 f1 = *(const float4*)(arow + kt * 32 + 4);
                bf16x8 a;
                a[0] = (short)f2bf(f0.x); a[1] = (short)f2bf(f0.y);
                a[2] = (short)f2bf(f0.z); a[3] = (short)f2bf(f0.w);
                a[4] = (short)f2bf(f1.x); a[5] = (short)f2bf(f1.y);
                a[6] = (short)f2bf(f1.z); a[7] = (short)f2bf(f1.w);
                afr[kt] = a;
            }

            f32x4 acc[8];
            #pragma unroll
            for (int nt = 0; nt < 8; ++nt) acc[nt] = (f32x4){0.f, 0.f, 0.f, 0.f};
            #pragma unroll
            for (int nt = 0; nt < 8; ++nt) {
                const unsigned short* wrow = &Wt[(nt * 16 + lrow) * WT_LD + lk * 8];
                #pragma unroll
                for (int kt = 0; kt < 4; ++kt) {
                    const bf16x8 b = *(const bf16x8*)(wrow + kt * 32);
                    acc[nt] = __builtin_amdgcn_mfma_f32_16x16x32_bf16(afr[kt], b, acc[nt], 0, 0, 0);
                }
            }

            // C layout: col = lane&15, row = (lane>>4)*4 + reg  (m89-verified)
            #pragma unroll
            for (int nt = 0; nt < 8; ++nt) {
                const int c = nt * 16 + lrow;
                #pragma unroll
                for (int r = 0; r < 4; ++r)
                    feat_bf[(size_t)(m0 + lk * 4 + r) * C_FEATS + c] = __float2bfloat16(acc[nt][r]);
            }
            float aw[8];
            #pragma unroll
            for (int nt = 0; nt < 8; ++nt) aw[nt] = attn_src[nt * 16 + lrow];
            #pragma unroll
            for (int h = 0; h < NUM_HEADS; ++h) {
                #pragma unroll
                for (int r = 0; r < 4; ++r) {
                    float v = acc[2 * h][r] * aw[2 * h] + acc[2 * h + 1][r] * aw[2 * h + 1];
                    v += __shfl_xor(v, 1);
                    v += __shfl_xor(v, 2);
                    v += __shfl_xor(v, 4);
                    v += __shfl_xor(v, 8);
                    if (lrow == 0) s_buf[(m0 + lk * 4 + r) * NUM_HEADS + h] = v;
                }
            }
        }
    } else {
        const int nthreads = (K1_BLK - PROJ_BLKS) * K1_THR;
        for (int p = (bid - PROJ_BLKS) * K1_THR + t; p < P; p += nthreads) {
            const int e = edge_idx[p];
            const int s = src_idx[p];
            const int pos = atomicAdd(&cursor[e * CUR_STRIDE], 1);
            if (pos < MAXD) edge_nodes[e * MAXD + pos] = s;
            const int prev = (p == 0) ? -1 : src_idx[p - 1];
            for (int n = prev + 1; n <= s; ++n) node_start[n] = p;
            if (p == P - 1)
                for (int n = s + 1; n <= N_NODES; ++n) node_start[n] = P;
        }
    }
}

// ---------------------------------------------------------------------------
// K2: per-edge softmax + aggregation. Block = 1 edge (2000 blocks), 512 thr =
// 8 wave-substreams; edge-proj heads parallel across waves 0..3.
// Max-free softmax; staging padded to x32 with w=0 -> branch-free aggregation.
// ---------------------------------------------------------------------------
__global__ __launch_bounds__(512) void edge_attn_kernel(
    const float* __restrict__ s_buf, const float* __restrict__ edge_feat,
    const float* __restrict__ attn_edge, const __hip_bfloat16* __restrict__ feat_bf,
    const int* __restrict__ cursor, const int* __restrict__ edge_nodes,
    __hip_bfloat16* __restrict__ hef)
{
    __shared__ float4 w_sh[MAXD];
    __shared__ int    n_sh[MAXD];
    __shared__ float  te_sh[NUM_HEADS];
    __shared__ float  inv_sh[NUM_HEADS];
    __shared__ float  wred[8][NUM_HEADS];
    __shared__ float  red[8][C_FEATS];

    const int e = blockIdx.x;
    const int t = threadIdx.x;
    const int wv = t >> 6, lane = t & 63;

    // fused edge projection: wave wv (0..3) computes head wv
    if (wv < NUM_HEADS) {
        const float v = (lane < EDGE_DIM) ? edge_feat[e * EDGE_DIM + lane] *
                                            attn_edge[wv * EDGE_DIM + lane] : 0.f;
        float p = v;
        p += __shfl_xor(p, 32); p += __shfl_xor(p, 16); p += __shfl_xor(p, 8);
        p += __shfl_xor(p, 4);  p += __shfl_xor(p, 2);  p += __shfl_xor(p, 1);
        if (lane == 0) te_sh[wv] = p;
    }
    __syncthreads();

    const int m = min(cursor[e * CUR_STRIDE], MAXD);
    const int m_pad = (m + 31) & ~31;

    float ps0 = 0.f, ps1 = 0.f, ps2 = 0.f, ps3 = 0.f;
    if (t < m) {
        const int n = edge_nodes[e * MAXD + t];
        n_sh[t] = n;
        const float4 s4 = *(const float4*)&s_buf[n * NUM_HEADS];
        float4 w;
        w.x = __expf(leaky(s4.x + te_sh[0]));
        w.y = __expf(leaky(s4.y + te_sh[1]));
        w.z = __expf(leaky(s4.z + te_sh[2]));
        w.w = __expf(leaky(s4.w + te_sh[3]));
        w_sh[t] = w;
        ps0 = w.x; ps1 = w.y; ps2 = w.z; ps3 = w.w;
    } else if (t < m_pad) {
        n_sh[t] = 0;
        w_sh[t] = make_float4(0.f, 0.f, 0.f, 0.f);   // exact no-op in all sums
    }
    #pragma unroll
    for (int d = 32; d >= 1; d >>= 1) {
        ps0 += __shfl_xor(ps0, d); ps1 += __shfl_xor(ps1, d);
        ps2 += __shfl_xor(ps2, d); ps3 += __shfl_xor(ps3, d);
    }
    if (lane == 0) {
        wred[wv][0] = ps0; wred[wv][1] = ps1; wred[wv][2] = ps2; wred[wv][3] = ps3;
    }
    __syncthreads();
    if (t < NUM_HEADS) {
        float s = 0.f;
        #pragma unroll
        for (int w8 = 0; w8 < 8; ++w8) s += wred[w8][t];
        inv_sh[t] = 1.f / (s + 1e-9f);
    }
    __syncthreads();

    // aggregation: substream wv (0..7) handles j = wv, wv+8, ...; branch-free
    const int c0 = lane * 2;
    const int h = lane >> 4;
    float a0 = 0.f, a1 = 0.f;
    const unsigned short* fb = (const unsigned short*)feat_bf;
    #pragma unroll 8
    for (int j = wv; j < m_pad; j += 8) {
        const int n = n_sh[j];
        const float w = ((const float*)&w_sh[j])[h];
        const unsigned v = *(const unsigned*)(fb + (size_t)n * C_FEATS + c0);
        a0 += w * __uint_as_float(v << 16);
        a1 += w * __uint_as_float(v & 0xffff0000u);
    }
    red[wv][c0] = a0;
    red[wv][c0 + 1] = a1;
    __syncthreads();
    if (t < C_FEATS) {
        float r = 0.f;
        #pragma unroll
        for (int w8 = 0; w8 < 8; ++w8) r += red[w8][t];
        hef[e * C_FEATS + t] = __float2bfloat16(r * inv_sh[t >> 5]);
    }
}

// ---------------------------------------------------------------------------
// K3: disseminate. 2500 blocks x 8 nodes, 256 threads = 4 waves; each wave
// owns 2 nodes, each lane 2 bf16 channels -> one wave load = one full 256B
// hef row (hef 512KB, L2-resident).
// ---------------------------------------------------------------------------
#define K3_NODES 8
#define K3_CHUNK 512
__global__ __launch_bounds__(256) void disseminate_kernel(
    const int* __restrict__ node_start, const int* __restrict__ edge_idx,
    const __hip_bfloat16* __restrict__ hef, float* __restrict__ out)
{
    __shared__ int e_sh[K3_CHUNK];
    __shared__ int ns_sh[K3_NODES + 1];
    const int t = threadIdx.x;
    const int wv = t >> 6, lane = t & 63;
    const int c0 = lane * 2;
    const int n0 = blockIdx.x * K3_NODES;

    if (t < K3_NODES + 1) ns_sh[t] = node_start[n0 + t];
    __syncthreads();
    const int s0 = ns_sh[0], s1 = ns_sh[K3_NODES];

    float a00 = 0.f, a01 = 0.f, a10 = 0.f, a11 = 0.f;  // [node r][chan 0/1]
    const unsigned short* hu = (const unsigned short*)hef;

    for (int cb = s0; cb < s1; cb += K3_CHUNK) {
        const int ccnt = min(K3_CHUNK, s1 - cb);
        __syncthreads();
        for (int i = t; i < ccnt; i += 256) e_sh[i] = edge_idx[cb + i];
        __syncthreads();
        {
            const int jlo = max(ns_sh[wv * 2], cb);
            const int jhi = min(ns_sh[wv * 2 + 1], cb + ccnt);
            #pragma unroll 8
            for (int j = jlo; j < jhi; ++j) {
                const unsigned v = *(const unsigned*)(hu + (size_t)e_sh[j - cb] * C_FEATS + c0);
                a00 += __uint_as_float(v << 16);
                a01 += __uint_as_float(v & 0xffff0000u);
            }
        }
        {
            const int jlo = max(ns_sh[wv * 2 + 1], cb);
            const int jhi = min(ns_sh[wv * 2 + 2], cb + ccnt);
            #pragma unroll 8
            for (int j = jlo; j < jhi; ++j) {
                const unsigned v = *(const unsigned*)(hu + (size_t)e_sh[j - cb] * C_FEATS + c0);
                a10 += __uint_as_float(v << 16);
                a11 += __uint_as_float(v & 0xffff0000u);
            }
        }
    }
    *(float2*)&out[(size_t)(n0 + wv * 2)     * C_FEATS + c0] = make_float2(a00, a01);
    *(float2*)&out[(size_t)(n0 + wv * 2 + 1) * C_FEATS + c0] = make_float2(a10, a11);
}

extern "C" void kernel_launch(void* const* d_in, const int* in_sizes, int n_in,
                              void* d_out, int out_size, void* d_ws, size_t ws_size,
                              hipStream_t stream) {
    const float* feat      = (const float*)d_in[0];
    const float* edge_feat = (const float*)d_in[1];
    // d_in[2] = H (dense incidence) — intentionally unused
    const float* fc_w      = (const float*)d_in[3];
    const float* attn_src  = (const float*)d_in[4];
    const float* attn_edge = (const float*)d_in[5];
    const int*   src_idx   = (const int*)d_in[6];
    const int*   edge_idx  = (const int*)d_in[7];
    const int P = in_sizes[6];
    float* out = (float*)d_out;

    float* ws = (float*)d_ws;
    float*          s_buf      = ws;                                          // 20000*4 f32
    __hip_bfloat16* hef        = (__hip_bfloat16*)(s_buf + N_NODES * NUM_HEADS); // 2000*128 bf16
    __hip_bfloat16* feat_bf    = hef + N_EDGES * C_FEATS;                     // 20000*128 bf16
    int*            node_start = (int*)(feat_bf + (size_t)N_NODES * C_FEATS); // 20001
    int*            edge_nodes = node_start + (N_NODES + 1);                  // 2000*MAXD
    int*            cursor     = edge_nodes + N_EDGES * MAXD;                 // 2000*CUR_STRIDE (16B-aligned)
    unsigned short* wt_g       = (unsigned short*)(cursor + N_EDGES * CUR_STRIDE); // 128*128 bf16

    prep_kernel<<<64, 256, 0, stream>>>((f32x4*)cursor, fc_w, wt_g);
    proj_scatter_kernel<<<K1_BLK, K1_THR, 0, stream>>>(
        feat, wt_g, attn_src, src_idx, edge_idx, P,
        feat_bf, s_buf, cursor, node_start, edge_nodes);
    edge_attn_kernel<<<N_EDGES, 512, 0, stream>>>(
        s_buf, edge_feat, attn_edge, feat_bf, cursor, edge_nodes, hef);
    disseminate_kernel<<<N_NODES / K3_NODES, 256, 0, stream>>>(
        node_start, edge_idx, hef, out);
}